// Round 3
// baseline (401.358 us; speedup 1.0000x reference)
//
#include <hip/hip_runtime.h>

#define NGRAPH 256
#define FIN 64
#define HID 32
#define NB_SHIFT 7            // 128 nodes per bucket
#define NB_NODES 128
#define KMAX 1024
#define EPB 2048              // edges per partB block
#define EPT 8                 // edges per thread (256 threads)

// ---------- node GEMMs ----------
__global__ __launch_bounds__(256) void node_lin64(
    const float* __restrict__ x, const float* __restrict__ Wrel,
    const float* __restrict__ Wroot, const float* __restrict__ bias,
    float* __restrict__ A, float* __restrict__ B, int N)
{
    __shared__ float sWr[FIN * HID];
    __shared__ float sWo[FIN * HID];
    __shared__ float sb[HID];
    __shared__ float sx[8 * FIN];
    int tid = threadIdx.x;
    for (int i = tid; i < FIN * HID; i += 256) { sWr[i] = Wrel[i]; sWo[i] = Wroot[i]; }
    if (tid < HID) sb[tid] = bias[tid];
    int base = blockIdx.x * 8;
    for (int i = tid; i < 8 * FIN; i += 256) {
        int n = base + i / FIN;
        sx[i] = (n < N) ? x[(size_t)n * FIN + (i % FIN)] : 0.f;
    }
    __syncthreads();
    int nl = tid >> 5, f = tid & 31, n = base + nl;
    if (n >= N) return;
    float ar = 0.f, ao = 0.f;
    #pragma unroll
    for (int k = 0; k < FIN; ++k) {
        float xv = sx[nl * FIN + k];
        ar = fmaf(xv, sWr[k * HID + f], ar);
        ao = fmaf(xv, sWo[k * HID + f], ao);
    }
    A[(size_t)n * HID + f] = ar;
    B[(size_t)n * HID + f] = ao + sb[f];
}

__global__ __launch_bounds__(256) void node_lin32(
    const float* __restrict__ Hpre, const float* __restrict__ Wrel,
    const float* __restrict__ Wroot, const float* __restrict__ bias,
    float* __restrict__ A, float* __restrict__ C, int N)
{
    __shared__ float sWr[HID * HID];
    __shared__ float sWo[HID * HID];
    __shared__ float sb[HID];
    __shared__ float sh[8 * HID];
    int tid = threadIdx.x;
    for (int i = tid; i < HID * HID; i += 256) { sWr[i] = Wrel[i]; sWo[i] = Wroot[i]; }
    if (tid < HID) sb[tid] = bias[tid];
    int base = blockIdx.x * 8;
    for (int i = tid; i < 8 * HID; i += 256) {
        int n = base + i / HID;
        float v = (n < N) ? Hpre[(size_t)n * HID + (i % HID)] : 0.f;
        sh[i] = v > 0.f ? v : 0.f;
    }
    __syncthreads();
    int nl = tid >> 5, f = tid & 31, n = base + nl;
    if (n >= N) return;
    float ar = 0.f, ao = 0.f;
    #pragma unroll
    for (int k = 0; k < HID; ++k) {
        float hv = sh[nl * HID + k];
        ar = fmaf(hv, sWr[k * HID + f], ar);
        ao = fmaf(hv, sWo[k * HID + f], ao);
    }
    A[(size_t)n * HID + f] = ar;
    C[(size_t)n * HID + f] = ao + sb[f];
}

// ---------- CSR build ----------
__global__ __launch_bounds__(256) void hist_kernel(
    const int* __restrict__ dst, int* __restrict__ cnt, int E)
{
    int i = blockIdx.x * 256 + threadIdx.x;
    int e = i * 4;
    if (e + 3 < E) {
        int4 d = *reinterpret_cast<const int4*>(dst + e);
        atomicAdd(&cnt[d.x], 1); atomicAdd(&cnt[d.y], 1);
        atomicAdd(&cnt[d.z], 1); atomicAdd(&cnt[d.w], 1);
    } else {
        for (; e < E; ++e) atomicAdd(&cnt[dst[e]], 1);
    }
}

__global__ __launch_bounds__(256) void scanA(
    const int* __restrict__ cnt, int* __restrict__ rowptr1,
    int* __restrict__ blockSums, int N)
{
    __shared__ int lds[256];
    int t = threadIdx.x;
    int base = blockIdx.x * 1024 + t * 4;
    int v0 = (base + 0 < N) ? cnt[base + 0] : 0;
    int v1 = (base + 1 < N) ? cnt[base + 1] : 0;
    int v2 = (base + 2 < N) ? cnt[base + 2] : 0;
    int v3 = (base + 3 < N) ? cnt[base + 3] : 0;
    int s = v0 + v1 + v2 + v3;
    lds[t] = s;
    __syncthreads();
    int acc = s;
    for (int off = 1; off < 256; off <<= 1) {
        int add = (t >= off) ? lds[t - off] : 0;
        __syncthreads();
        acc += add;
        lds[t] = acc;
        __syncthreads();
    }
    int run = acc - s;
    run += v0; if (base + 0 < N) rowptr1[base + 0] = run;
    run += v1; if (base + 1 < N) rowptr1[base + 1] = run;
    run += v2; if (base + 2 < N) rowptr1[base + 2] = run;
    run += v3; if (base + 3 < N) rowptr1[base + 3] = run;
    if (t == 255) blockSums[blockIdx.x] = acc;
}

__global__ void scanB(const int* __restrict__ blockSums,
                      int* __restrict__ blockOff, int* __restrict__ rowptr,
                      int* __restrict__ ncur, int nb)
{
    if (threadIdx.x == 0 && blockIdx.x == 0) {
        int run = 0;
        for (int b = 0; b < nb; ++b) { blockOff[b] = run; run += blockSums[b]; }
        rowptr[0] = 0;
        ncur[0] = 0;
    }
}

// finalize rowptr[1..N] and mirror into ncur (per-node fill cursors)
__global__ __launch_bounds__(256) void scanC(
    int* __restrict__ rowptr1, int* __restrict__ ncur1,
    const int* __restrict__ blockOff, int N)
{
    int b = blockIdx.x;
    int off = blockOff[b];
    int base = b * 1024 + threadIdx.x * 4;
    #pragma unroll
    for (int k = 0; k < 4; ++k)
        if (base + k < N) {
            int v = rowptr1[base + k] + off;
            rowptr1[base + k] = v;
            ncur1[base + k] = v;
        }
}

// per-bucket staging cursors: bcur[b] = rowptr[min(b*128, N)]
__global__ void initb_kernel(const int* __restrict__ rowptr,
                             int* __restrict__ bcur, int N, int K)
{
    int b = threadIdx.x + blockIdx.x * blockDim.x;
    if (b < K) {
        int n = b << NB_SHIFT;
        if (n > N) n = N;
        bcur[b] = rowptr[n];
    }
}

// partition pass 1: edges -> bucket-contiguous staging (coalesced run writes)
__global__ __launch_bounds__(256) void partB(
    const int* __restrict__ src, const int* __restrict__ dst,
    const float* __restrict__ ew, int* __restrict__ bcur,
    int4* __restrict__ stg, int E, int K)
{
    __shared__ int4 pay[EPB];
    __shared__ int h[KMAX];     // hist, then reused as LDS cursor
    __shared__ int lofs[KMAX];
    __shared__ int gb[KMAX];
    __shared__ int sc[256];
    int tid = threadIdx.x;
    for (int i = tid; i < K; i += 256) h[i] = 0;
    __syncthreads();

    int base = blockIdx.x * EPB;
    int es[EPT], ds[EPT]; float wsr[EPT];
    #pragma unroll
    for (int k = 0; k < EPT; ++k) {
        int e = base + k * 256 + tid;
        if (e < E) {
            es[k] = src[e]; ds[k] = dst[e]; wsr[k] = ew[e];
            atomicAdd(&h[ds[k] >> NB_SHIFT], 1);
        } else ds[k] = -1;
    }
    __syncthreads();

    // block-scan hist over K buckets (thread t owns buckets [t*4, t*4+4))
    int b0 = tid * 4;
    int v[4], s = 0;
    #pragma unroll
    for (int j = 0; j < 4; ++j) { int b = b0 + j; v[j] = (b < K) ? h[b] : 0; s += v[j]; }
    sc[tid] = s;
    __syncthreads();
    int acc = s;
    for (int off = 1; off < 256; off <<= 1) {
        int add = (tid >= off) ? sc[tid - off] : 0;
        __syncthreads();
        acc += add;
        sc[tid] = acc;
        __syncthreads();
    }
    int run = acc - s;
    #pragma unroll
    for (int j = 0; j < 4; ++j) {
        int b = b0 + j;
        if (b < K) lofs[b] = run;
        run += v[j];
    }
    __syncthreads();

    // reserve global staging space; convert h[] into LDS scatter cursors
    for (int b = tid; b < K; b += 256) {
        int c = h[b];
        gb[b] = c ? atomicAdd(&bcur[b], c) : 0;
        h[b] = lofs[b];
    }
    __syncthreads();

    // scatter edges into LDS, bucket-grouped, with final global target in .w
    #pragma unroll
    for (int k = 0; k < EPT; ++k) {
        if (ds[k] >= 0) {
            int b = ds[k] >> NB_SHIFT;
            int slot = atomicAdd(&h[b], 1);
            pay[slot] = make_int4(es[k], __float_as_int(wsr[k]), ds[k],
                                  gb[b] + slot - lofs[b]);
        }
    }
    __syncthreads();

    // coalesced run writes to staging
    int tot = E - base; if (tot > EPB) tot = EPB;
    for (int i = tid; i < tot; i += 256) {
        int4 p = pay[i];
        stg[p.w] = make_int4(p.x, p.y, p.z, 0);
    }
}

// partition pass 2: one block per bucket, scatter within L2-local window
__global__ __launch_bounds__(256) void partC(
    const int* __restrict__ rowptr, const int4* __restrict__ stg,
    int* __restrict__ ncur, int2* __restrict__ perm, int N)
{
    int b = blockIdx.x;
    int n0 = b << NB_SHIFT;
    int n1 = n0 + NB_NODES; if (n1 > N) n1 = N;
    if (n0 >= N) return;
    int lo = rowptr[n0], hi = rowptr[n1];
    for (int t = lo + threadIdx.x; t < hi; t += 256) {
        int4 v = stg[t];
        int pos = atomicAdd(&ncur[v.z], 1);
        perm[pos] = make_int2(v.x, v.y);
    }
}

// ---------- gather-side aggregation ----------
// 64 lanes per node: two halves of edge list, xor-combine, 2-way unroll
__global__ __launch_bounds__(256) void csr_agg(
    const int* __restrict__ rowptr, const int2* __restrict__ perm,
    const float* __restrict__ A, float* __restrict__ out, int N)
{
    int gid = blockIdx.x * 256 + threadIdx.x;
    int n = gid >> 6;
    if (n >= N) return;
    int half = (threadIdx.x >> 5) & 1;
    int f = threadIdx.x & 31;
    int e0 = rowptr[n], e1 = rowptr[n + 1];
    float a0 = 0.f, a1 = 0.f;
    int e = e0 + half;
    for (; e + 2 < e1; e += 4) {
        int2 p0 = perm[e];
        int2 p1 = perm[e + 2];
        a0 = fmaf(A[(size_t)p0.x * HID + f], __int_as_float(p0.y), a0);
        a1 = fmaf(A[(size_t)p1.x * HID + f], __int_as_float(p1.y), a1);
    }
    for (; e < e1; e += 2) {
        int2 p = perm[e];
        a0 = fmaf(A[(size_t)p.x * HID + f], __int_as_float(p.y), a0);
    }
    float acc = a0 + a1;
    acc += __shfl_xor(acc, 32, 64);
    if (half == 0) out[(size_t)n * HID + f] += acc;
}

// ---------- pool + MLP ----------
__global__ __launch_bounds__(256) void pool_kernel(
    const float* __restrict__ C, const int* __restrict__ batch,
    float* __restrict__ sums, float* __restrict__ cnts, int N)
{
    int f = threadIdx.x & 31, g = threadIdx.x >> 5;
    int n0 = blockIdx.x * 256 + g * 32;
    if (n0 >= N) return;
    int n1 = n0 + 32; if (n1 > N) n1 = N;
    int cur = batch[n0];
    float acc = 0.f, cnt = 0.f;
    for (int n = n0; n < n1; ++n) {
        int b = batch[n];
        if (b != cur) {
            atomicAdd(&sums[cur * HID + f], acc);
            if (f == 0) atomicAdd(&cnts[cur], cnt);
            acc = 0.f; cnt = 0.f; cur = b;
        }
        float v = C[(size_t)n * HID + f];
        acc += v > 0.f ? v : 0.f;
        cnt += 1.f;
    }
    atomicAdd(&sums[cur * HID + f], acc);
    if (f == 0) atomicAdd(&cnts[cur], cnt);
}

__global__ __launch_bounds__(256) void mlp_kernel(
    const float* __restrict__ sums, const float* __restrict__ cnts,
    const float* __restrict__ W1, const float* __restrict__ b1,
    const float* __restrict__ W2, const float* __restrict__ b2,
    const float* __restrict__ W3, const float* __restrict__ b3,
    float* __restrict__ out)
{
    __shared__ float sW1[32 * 32], sb1[32], sW2[32 * 16], sb2[16], sW3[16], sb3;
    int tid = threadIdx.x;
    for (int i = tid; i < 32 * 32; i += 256) sW1[i] = W1[i];
    for (int i = tid; i < 32 * 16; i += 256) sW2[i] = W2[i];
    if (tid < 32) sb1[tid] = b1[tid];
    if (tid < 16) { sb2[tid] = b2[tid]; sW3[tid] = W3[tid]; }
    if (tid == 0) sb3 = b3[0];
    __syncthreads();
    int gi = tid;
    float c = cnts[gi]; c = c > 1.f ? c : 1.f;
    float inv = 1.f / c;
    float gvec[32];
    #pragma unroll
    for (int i = 0; i < 32; ++i) gvec[i] = sums[gi * 32 + i] * inv;
    float h1[32];
    #pragma unroll
    for (int j = 0; j < 32; ++j) {
        float a = sb1[j];
        #pragma unroll
        for (int k = 0; k < 32; ++k) a = fmaf(gvec[k], sW1[k * 32 + j], a);
        h1[j] = a > 0.f ? a : 0.f;
    }
    float o = sb3;
    #pragma unroll
    for (int j = 0; j < 16; ++j) {
        float a = sb2[j];
        #pragma unroll
        for (int k = 0; k < 32; ++k) a = fmaf(h1[k], sW2[k * 16 + j], a);
        a = a > 0.f ? a : 0.f;
        o = fmaf(a, sW3[j], o);
    }
    out[gi] = o;
}

extern "C" void kernel_launch(void* const* d_in, const int* in_sizes, int n_in,
                              void* d_out, int out_size, void* d_ws, size_t ws_size,
                              hipStream_t stream) {
    const float* x     = (const float*)d_in[0];
    const int*   ei    = (const int*)d_in[1];
    const float* ew    = (const float*)d_in[2];
    const int*   batch = (const int*)d_in[3];
    const float* c1rw  = (const float*)d_in[4];
    const float* c1rb  = (const float*)d_in[5];
    const float* c1ow  = (const float*)d_in[6];
    const float* c2rw  = (const float*)d_in[7];
    const float* c2rb  = (const float*)d_in[8];
    const float* c2ow  = (const float*)d_in[9];
    const float* l1w   = (const float*)d_in[10];
    const float* l1b   = (const float*)d_in[11];
    const float* l2w   = (const float*)d_in[12];
    const float* l2b   = (const float*)d_in[13];
    const float* lw    = (const float*)d_in[14];
    const float* lb    = (const float*)d_in[15];

    int N = in_sizes[0] / FIN;      // 100000
    int E = in_sizes[2];            // 1600000
    const int* src = ei;
    const int* dst = ei + E;
    int K = (N + NB_NODES - 1) >> NB_SHIFT;   // 782 buckets

    // ---- workspace layout ----
    char* ws = (char*)d_ws;
    size_t off = 0;
    auto alloc = [&](size_t nbytes) { void* p = ws + off; off += (nbytes + 15) & ~size_t(15); return p; };
    float* A       = (float*)alloc((size_t)N * HID * 4);
    float* B       = (float*)alloc((size_t)N * HID * 4);
    float* C       = (float*)alloc((size_t)N * HID * 4);
    int*   cnt     = (int*)  alloc((size_t)N * 4);
    int*   rowptr  = (int*)  alloc((size_t)(N + 1) * 4);
    int*   ncur    = (int*)  alloc((size_t)(N + 1) * 4);
    int*   bcur    = (int*)  alloc((size_t)KMAX * 4);
    int*   bSums   = (int*)  alloc(256 * 4);
    int*   bOff    = (int*)  alloc(256 * 4);
    int2*  perm    = (int2*) alloc((size_t)E * 8);
    float* sums    = (float*)alloc(NGRAPH * HID * 4);
    float* cnts    = (float*)alloc(NGRAPH * 4);
    // staging buffer aliases A+B (both are written only after partC)
    int4*  stg     = (int4*)A;     // E*16 bytes == 2 * N*HID*4 bytes

    hipMemsetAsync(cnt, 0, (size_t)N * 4, stream);
    hipMemsetAsync(sums, 0, (NGRAPH * HID + NGRAPH) * 4, stream);

    int nb_hist = (E / 4 + 255) / 256;
    int nb_scan = (N + 1023) / 1024;
    int nb_node = (N + 7) / 8;
    int nb_agg  = (int)(((long long)N * 64 + 255) / 256);
    int nb_partB = (E + EPB - 1) / EPB;

    // CSR build + dst-partition
    hist_kernel<<<nb_hist, 256, 0, stream>>>(dst, cnt, E);
    scanA<<<nb_scan, 256, 0, stream>>>(cnt, rowptr + 1, bSums, N);
    scanB<<<1, 64, 0, stream>>>(bSums, bOff, rowptr, ncur, nb_scan);
    scanC<<<nb_scan, 256, 0, stream>>>(rowptr + 1, ncur + 1, bOff, N);
    initb_kernel<<<1, KMAX, 0, stream>>>(rowptr, bcur, N, K);
    partB<<<nb_partB, 256, 0, stream>>>(src, dst, ew, bcur, stg, E, K);
    partC<<<K, 256, 0, stream>>>(rowptr, stg, ncur, perm, N);

    // conv1
    node_lin64<<<nb_node, 256, 0, stream>>>(x, c1rw, c1ow, c1rb, A, B, N);
    csr_agg<<<nb_agg, 256, 0, stream>>>(rowptr, perm, A, B, N);
    // conv2
    node_lin32<<<nb_node, 256, 0, stream>>>(B, c2rw, c2ow, c2rb, A, C, N);
    csr_agg<<<nb_agg, 256, 0, stream>>>(rowptr, perm, A, C, N);
    // pool + MLP
    pool_kernel<<<(N + 255) / 256, 256, 0, stream>>>(C, batch, sums, cnts, N);
    mlp_kernel<<<1, 256, 0, stream>>>(sums, cnts, l1w, l1b, l2w, l2b, lw, lb,
                                      (float*)d_out);
}